// Round 1
// baseline (378.715 us; speedup 1.0000x reference)
//
#include <hip/hip_runtime.h>
#include <hip/hip_bf16.h>
#include <math.h>

typedef __attribute__((ext_vector_type(4))) float f32x4;
typedef __attribute__((ext_vector_type(8))) short short8;
typedef __attribute__((ext_vector_type(4))) unsigned short ushort4_t;

#define B_  4
#define S_  2048
#define D_  1024
#define NH_ 16
#define HD_ 64

__device__ __forceinline__ unsigned short f2bf(float f) {
  unsigned u = __builtin_bit_cast(unsigned, f);
  u += 0x7FFFu + ((u >> 16) & 1u);   // RNE
  return (unsigned short)(u >> 16);
}

__device__ __forceinline__ void gload_lds16(const void* g, void* l) {
  __builtin_amdgcn_global_load_lds(
      (const __attribute__((address_space(1))) unsigned int*)g,
      (__attribute__((address_space(3))) unsigned int*)l, 16, 0, 0);
}

// ---------------- fp32 -> bf16 convert ----------------
__global__ void cvt_f32_to_bf16(const float* __restrict__ in,
                                unsigned short* __restrict__ out, int n4) {
  int i = blockIdx.x * 256 + threadIdx.x;
  if (i >= n4) return;
  const float4 f = reinterpret_cast<const float4*>(in)[i];
  ushort4_t r;
  r.x = f2bf(f.x); r.y = f2bf(f.y); r.z = f2bf(f.z); r.w = f2bf(f.w);
  reinterpret_cast<ushort4_t*>(out)[i] = r;
}

// ---------------- GEMM: C[M,N] = A[M,K] @ W[N,K]^T + bias ----------------
// M=8192, N=1024, K=1024. 128x128 tile, BK=64, 4 waves (2x2 of 64x64).
// LDS tiles XOR-swizzled (byte ^= (row&7)<<4), staged with linear-dest
// global_load_lds from inverse-swizzled global source.
template <int TRANS_V, int OUT_F32>
__global__ __launch_bounds__(256) void gemm_bt(
    const unsigned short* __restrict__ A,
    const unsigned short* __restrict__ W,
    const float* __restrict__ bias,
    void* __restrict__ Cout) {
  constexpr int K = 1024;
  __shared__ unsigned short At[128 * 64];
  __shared__ unsigned short Wt[128 * 64];
  const int tid = threadIdx.x;
  const int wave = tid >> 6, lane = tid & 63;
  const int m0 = blockIdx.y * 128, n0 = blockIdx.x * 128;
  f32x4 acc[4][4] = {};

  const int srow = tid >> 3;   // staging row (+c*32)
  const int scol8 = tid & 7;   // staging 8-elem chunk

  for (int kt = 0; kt < K; kt += 64) {
#pragma unroll
    for (int c = 0; c < 4; ++c) {
      const int row = c * 32 + srow;
      const int col = (scol8 ^ (row & 7)) << 3;
      gload_lds16(A + (size_t)(m0 + row) * K + kt + col,
                  (char*)At + c * 4096 + wave * 1024);
    }
#pragma unroll
    for (int c = 0; c < 4; ++c) {
      const int row = c * 32 + srow;
      const int col = (scol8 ^ (row & 7)) << 3;
      gload_lds16(W + (size_t)(n0 + row) * K + kt + col,
                  (char*)Wt + c * 4096 + wave * 1024);
    }
    asm volatile("s_waitcnt vmcnt(0)" ::: "memory");
    __syncthreads();

    const int wr = (wave >> 1) * 64, wc = (wave & 1) * 64;
#pragma unroll
    for (int kk = 0; kk < 2; ++kk) {
      short8 af[4], wf[4];
#pragma unroll
      for (int m = 0; m < 4; ++m) {
        const int row = wr + m * 16 + (lane & 15);
        const int colb = ((kk * 32 + (lane >> 4) * 8) * 2) ^ ((row & 7) << 4);
        af[m] = *(const short8*)((const char*)At + row * 128 + colb);
      }
#pragma unroll
      for (int n = 0; n < 4; ++n) {
        const int row = wc + n * 16 + (lane & 15);
        const int colb = ((kk * 32 + (lane >> 4) * 8) * 2) ^ ((row & 7) << 4);
        wf[n] = *(const short8*)((const char*)Wt + row * 128 + colb);
      }
#pragma unroll
      for (int m = 0; m < 4; ++m)
#pragma unroll
        for (int n = 0; n < 4; ++n)
          acc[m][n] = __builtin_amdgcn_mfma_f32_16x16x32_bf16(af[m], wf[n], acc[m][n], 0, 0, 0);
    }
    __syncthreads();
  }

  // epilogue
  const int wr = (wave >> 1) * 64, wc = (wave & 1) * 64;
  const int g = lane >> 4, cl = lane & 15;
#pragma unroll
  for (int m = 0; m < 4; ++m) {
#pragma unroll
    for (int n = 0; n < 4; ++n) {
      const int ng = n0 + wc + n * 16 + cl;
      const float bv = bias[ng];
      if (TRANS_V) {
        // V projection: write transposed Vt[b][hd][s], pack 4 consecutive s
        const int mg = m0 + wr + m * 16 + g * 4;
        const int bb = mg >> 11;
        const int ss = mg & 2047;
        ushort4_t pk;
        pk.x = f2bf(acc[m][n][0] + bv);
        pk.y = f2bf(acc[m][n][1] + bv);
        pk.z = f2bf(acc[m][n][2] + bv);
        pk.w = f2bf(acc[m][n][3] + bv);
        *(ushort4_t*)((unsigned short*)Cout + ((size_t)bb * 1024 + ng) * 2048 + ss) = pk;
      } else {
#pragma unroll
        for (int r = 0; r < 4; ++r) {
          const int mg = m0 + wr + m * 16 + g * 4 + r;
          const float v = acc[m][n][r] + bv;
          if (OUT_F32)
            ((float*)Cout)[(size_t)mg * 1024 + ng] = v;
          else
            ((unsigned short*)Cout)[(size_t)mg * 1024 + ng] = f2bf(v);
        }
      }
    }
  }
}

// ---------------- flash attention (causal + padding mask) ----------------
// block = (b, h, 128 q rows); 4 waves x 32 rows. KV tiles of 64.
__global__ __launch_bounds__(256) void attn_fwd(
    const unsigned short* __restrict__ Qp,   // [B*S][1024]
    const unsigned short* __restrict__ Kp,   // [B*S][1024]
    const unsigned short* __restrict__ Vt,   // [B][1024][2048] (transposed)
    const unsigned char* __restrict__ pmask, // [B][2048]
    unsigned short* __restrict__ Out) {      // [B*S][1024]
  __shared__ unsigned short Kt[64 * 64];       // [kv][d], swizzled
  __shared__ unsigned short Vl[64 * 64];       // [d][kv], swizzled
  __shared__ unsigned short Pl[4][32 * 72];    // per-wave P, padded rows
  __shared__ unsigned char msk[64];

  const int tid = threadIdx.x;
  const int wave = tid >> 6, lane = tid & 63;
  const int g = lane >> 4, cl = lane & 15;
  const int bh = blockIdx.y, b = bh >> 4, h = bh & 15;
  const int q0 = blockIdx.x * 128;
  const int qw = q0 + wave * 32;

  // hoist Q fragments (A-operand layout)
  short8 qf[2][2];
#pragma unroll
  for (int m = 0; m < 2; ++m)
#pragma unroll
    for (int kk = 0; kk < 2; ++kk)
      qf[m][kk] = *(const short8*)(Qp + (size_t)(b * S_ + qw + m * 16 + cl) * D_ +
                                   h * HD_ + kk * 32 + g * 8);

  float mrow[2][4], lrow[2][4];
  f32x4 oacc[2][4] = {};
#pragma unroll
  for (int m = 0; m < 2; ++m)
#pragma unroll
    for (int r = 0; r < 4; ++r) { mrow[m][r] = -INFINITY; lrow[m][r] = 0.f; }

  const int srow = tid >> 3, scol8 = tid & 7;
  const int kvend = q0 + 128;
  for (int kv0 = 0; kv0 < kvend; kv0 += 64) {
#pragma unroll
    for (int c = 0; c < 2; ++c) {
      const int row = c * 32 + srow;
      const int col = (scol8 ^ (row & 7)) << 3;
      gload_lds16(Kp + (size_t)(b * S_ + kv0 + row) * D_ + h * HD_ + col,
                  (char*)Kt + c * 4096 + wave * 1024);
      gload_lds16(Vt + ((size_t)b * D_ + h * HD_ + row) * S_ + kv0 + col,
                  (char*)Vl + c * 4096 + wave * 1024);
    }
    if (tid < 64) msk[tid] = pmask[b * S_ + kv0 + tid];
    asm volatile("s_waitcnt vmcnt(0)" ::: "memory");
    __syncthreads();

    // S = Q @ K^T
    f32x4 sc[2][4] = {};
#pragma unroll
    for (int kk = 0; kk < 2; ++kk) {
      short8 kf[4];
#pragma unroll
      for (int n = 0; n < 4; ++n) {
        const int row = n * 16 + cl;
        const int colb = ((kk * 32 + g * 8) * 2) ^ ((row & 7) << 4);
        kf[n] = *(const short8*)((const char*)Kt + row * 128 + colb);
      }
#pragma unroll
      for (int m = 0; m < 2; ++m)
#pragma unroll
        for (int n = 0; n < 4; ++n)
          sc[m][n] = __builtin_amdgcn_mfma_f32_16x16x32_bf16(qf[m][kk], kf[n], sc[m][n], 0, 0, 0);
    }

    // scale + causal + padding mask
#pragma unroll
    for (int m = 0; m < 2; ++m)
#pragma unroll
      for (int n = 0; n < 4; ++n) {
        const int kv = kv0 + n * 16 + cl;
        const bool pmk = (msk[n * 16 + cl] != 0);
#pragma unroll
        for (int r = 0; r < 4; ++r) {
          const int qg = qw + m * 16 + g * 4 + r;
          const bool dead = (kv > qg) || pmk;
          sc[m][n][r] = dead ? -1e30f : sc[m][n][r] * 0.125f;
        }
      }

    // online softmax (row state lives in the 16-lane group)
#pragma unroll
    for (int m = 0; m < 2; ++m) {
#pragma unroll
      for (int r = 0; r < 4; ++r) {
        float mx = fmaxf(fmaxf(sc[m][0][r], sc[m][1][r]),
                         fmaxf(sc[m][2][r], sc[m][3][r]));
#pragma unroll
        for (int off = 1; off < 16; off <<= 1)
          mx = fmaxf(mx, __shfl_xor(mx, off, 64));
        const float mnew = fmaxf(mrow[m][r], mx);
        const float corr = __expf(mrow[m][r] - mnew);
        mrow[m][r] = mnew;
        float rs = 0.f;
#pragma unroll
        for (int n = 0; n < 4; ++n) {
          const float p = __expf(sc[m][n][r] - mnew);
          sc[m][n][r] = p;
          rs += p;
        }
#pragma unroll
        for (int off = 1; off < 16; off <<= 1)
          rs += __shfl_xor(rs, off, 64);
        lrow[m][r] = lrow[m][r] * corr + rs;
#pragma unroll
        for (int nd = 0; nd < 4; ++nd) oacc[m][nd][r] *= corr;
      }
    }

    // P -> LDS (bf16) to reach MFMA A-layout
    unsigned short* pw = &Pl[wave][0];
#pragma unroll
    for (int m = 0; m < 2; ++m)
#pragma unroll
      for (int n = 0; n < 4; ++n)
#pragma unroll
        for (int r = 0; r < 4; ++r)
          pw[(m * 16 + g * 4 + r) * 72 + n * 16 + cl] = f2bf(sc[m][n][r]);

    // O += P @ V
#pragma unroll
    for (int kk = 0; kk < 2; ++kk) {
      short8 pf[2], vf[4];
#pragma unroll
      for (int m = 0; m < 2; ++m)
        pf[m] = *(const short8*)(pw + (m * 16 + cl) * 72 + kk * 32 + g * 8);
#pragma unroll
      for (int nd = 0; nd < 4; ++nd) {
        const int row = nd * 16 + cl;
        const int colb = ((kk * 32 + g * 8) * 2) ^ ((row & 7) << 4);
        vf[nd] = *(const short8*)((const char*)Vl + row * 128 + colb);
      }
#pragma unroll
      for (int m = 0; m < 2; ++m)
#pragma unroll
        for (int nd = 0; nd < 4; ++nd)
          oacc[m][nd] = __builtin_amdgcn_mfma_f32_16x16x32_bf16(pf[m], vf[nd], oacc[m][nd], 0, 0, 0);
    }
    __syncthreads();
  }

  // normalize + write
#pragma unroll
  for (int m = 0; m < 2; ++m) {
    float inv[4];
#pragma unroll
    for (int r = 0; r < 4; ++r) inv[r] = 1.f / lrow[m][r];
#pragma unroll
    for (int nd = 0; nd < 4; ++nd)
#pragma unroll
      for (int r = 0; r < 4; ++r) {
        const int qg = qw + m * 16 + g * 4 + r;
        Out[(size_t)(b * S_ + qg) * D_ + h * HD_ + nd * 16 + cl] =
            f2bf(oacc[m][nd][r] * inv[r]);
      }
  }
}

// ---------------- launch ----------------
extern "C" void kernel_launch(void* const* d_in, const int* in_sizes, int n_in,
                              void* d_out, int out_size, void* d_ws, size_t ws_size,
                              hipStream_t stream) {
  (void)in_sizes; (void)n_in; (void)out_size; (void)ws_size;
  const float* q  = (const float*)d_in[0];
  const float* k  = (const float*)d_in[1];
  const float* v  = (const float*)d_in[2];
  const unsigned char* pm = (const unsigned char*)d_in[3];
  const float* Wq = (const float*)d_in[4];
  const float* bq = (const float*)d_in[5];
  const float* Wk = (const float*)d_in[6];
  const float* bk = (const float*)d_in[7];
  const float* Wv = (const float*)d_in[8];
  const float* bv = (const float*)d_in[9];
  const float* Wo = (const float*)d_in[10];
  const float* bo = (const float*)d_in[11];

  char* ws = (char*)d_ws;
  const size_t MB = 1024 * 1024;
  unsigned short* qb  = (unsigned short*)(ws + 0 * MB);
  unsigned short* kb  = (unsigned short*)(ws + 16 * MB);
  unsigned short* vb  = (unsigned short*)(ws + 32 * MB);
  unsigned short* Wqb = (unsigned short*)(ws + 48 * MB);
  unsigned short* Wkb = (unsigned short*)(ws + 50 * MB);
  unsigned short* Wvb = (unsigned short*)(ws + 52 * MB);
  unsigned short* Wob = (unsigned short*)(ws + 54 * MB);
  unsigned short* Qp  = (unsigned short*)(ws + 56 * MB);
  unsigned short* Kp  = (unsigned short*)(ws + 72 * MB);
  unsigned short* Vt  = (unsigned short*)(ws + 88 * MB);
  unsigned short* AO  = (unsigned short*)(ws + 104 * MB);

  const int n4_qkv = B_ * S_ * D_ / 4;  // 2,097,152
  const int n4_w   = 1024 * 1024 / 4;   // 262,144
  cvt_f32_to_bf16<<<dim3(n4_qkv / 256), dim3(256), 0, stream>>>(q, qb, n4_qkv);
  cvt_f32_to_bf16<<<dim3(n4_qkv / 256), dim3(256), 0, stream>>>(k, kb, n4_qkv);
  cvt_f32_to_bf16<<<dim3(n4_qkv / 256), dim3(256), 0, stream>>>(v, vb, n4_qkv);
  cvt_f32_to_bf16<<<dim3(n4_w / 256), dim3(256), 0, stream>>>(Wq, Wqb, n4_w);
  cvt_f32_to_bf16<<<dim3(n4_w / 256), dim3(256), 0, stream>>>(Wk, Wkb, n4_w);
  cvt_f32_to_bf16<<<dim3(n4_w / 256), dim3(256), 0, stream>>>(Wv, Wvb, n4_w);
  cvt_f32_to_bf16<<<dim3(n4_w / 256), dim3(256), 0, stream>>>(Wo, Wob, n4_w);

  dim3 gg(8, 64), gb(256);
  gemm_bt<0, 0><<<gg, gb, 0, stream>>>(qb, Wqb, bq, Qp);
  gemm_bt<0, 0><<<gg, gb, 0, stream>>>(kb, Wkb, bk, Kp);
  gemm_bt<1, 0><<<gg, gb, 0, stream>>>(vb, Wvb, bv, Vt);

  attn_fwd<<<dim3(S_ / 128, B_ * NH_), dim3(256), 0, stream>>>(Qp, Kp, Vt, pm, AO);

  gemm_bt<0, 1><<<gg, gb, 0, stream>>>(AO, Wob, bo, (float*)d_out);
}

// Round 2
// 280.264 us; speedup vs baseline: 1.3513x; 1.3513x over previous
//
#include <hip/hip_runtime.h>
#include <hip/hip_bf16.h>
#include <math.h>

typedef __attribute__((ext_vector_type(4))) float f32x4;
typedef __attribute__((ext_vector_type(8))) short short8;
typedef __attribute__((ext_vector_type(4))) unsigned short ushort4_t;

#define B_  4
#define S_  2048
#define D_  1024
#define NH_ 16
#define HD_ 64

__device__ __forceinline__ unsigned short f2bf(float f) {
  unsigned u = __builtin_bit_cast(unsigned, f);
  u += 0x7FFFu + ((u >> 16) & 1u);   // RNE
  return (unsigned short)(u >> 16);
}

__device__ __forceinline__ void gload_lds16(const void* g, void* l) {
  __builtin_amdgcn_global_load_lds(
      (const __attribute__((address_space(1))) unsigned int*)g,
      (__attribute__((address_space(3))) unsigned int*)l, 16, 0, 0);
}

// ---------------- fp32 -> bf16 converts (fused launches) ----------------
__global__ void cvt3_f32_to_bf16(const float* __restrict__ a,
                                 const float* __restrict__ b,
                                 const float* __restrict__ c,
                                 unsigned short* __restrict__ oa,
                                 unsigned short* __restrict__ ob,
                                 unsigned short* __restrict__ oc, int n4) {
  int i = blockIdx.x * 256 + threadIdx.x;
  if (i >= n4) return;
  const float* in = blockIdx.y == 0 ? a : (blockIdx.y == 1 ? b : c);
  unsigned short* out = blockIdx.y == 0 ? oa : (blockIdx.y == 1 ? ob : oc);
  const float4 f = reinterpret_cast<const float4*>(in)[i];
  ushort4_t r;
  r.x = f2bf(f.x); r.y = f2bf(f.y); r.z = f2bf(f.z); r.w = f2bf(f.w);
  reinterpret_cast<ushort4_t*>(out)[i] = r;
}

__global__ void cvt4_f32_to_bf16(const float* __restrict__ a,
                                 const float* __restrict__ b,
                                 const float* __restrict__ c,
                                 const float* __restrict__ d,
                                 unsigned short* __restrict__ oa,
                                 unsigned short* __restrict__ ob,
                                 unsigned short* __restrict__ oc,
                                 unsigned short* __restrict__ od, int n4) {
  int i = blockIdx.x * 256 + threadIdx.x;
  if (i >= n4) return;
  const float* in = blockIdx.y == 0 ? a : (blockIdx.y == 1 ? b : (blockIdx.y == 2 ? c : d));
  unsigned short* out = blockIdx.y == 0 ? oa : (blockIdx.y == 1 ? ob : (blockIdx.y == 2 ? oc : od));
  const float4 f = reinterpret_cast<const float4*>(in)[i];
  ushort4_t r;
  r.x = f2bf(f.x); r.y = f2bf(f.y); r.z = f2bf(f.z); r.w = f2bf(f.w);
  reinterpret_cast<ushort4_t*>(out)[i] = r;
}

// ---------------- GEMM: C[M,N] = A[M,K] @ W[N,K]^T + bias ----------------
template <int TRANS_V, int OUT_F32>
__global__ __launch_bounds__(256) void gemm_bt(
    const unsigned short* __restrict__ A,
    const unsigned short* __restrict__ W,
    const float* __restrict__ bias,
    void* __restrict__ Cout) {
  constexpr int K = 1024;
  __shared__ unsigned short At[128 * 64];
  __shared__ unsigned short Wt[128 * 64];
  const int tid = threadIdx.x;
  const int wave = tid >> 6, lane = tid & 63;
  const int m0 = blockIdx.y * 128, n0 = blockIdx.x * 128;
  f32x4 acc[4][4] = {};

  const int srow = tid >> 3;
  const int scol8 = tid & 7;

  for (int kt = 0; kt < K; kt += 64) {
#pragma unroll
    for (int c = 0; c < 4; ++c) {
      const int row = c * 32 + srow;
      const int col = (scol8 ^ (row & 7)) << 3;
      gload_lds16(A + (size_t)(m0 + row) * K + kt + col,
                  (char*)At + c * 4096 + wave * 1024);
    }
#pragma unroll
    for (int c = 0; c < 4; ++c) {
      const int row = c * 32 + srow;
      const int col = (scol8 ^ (row & 7)) << 3;
      gload_lds16(W + (size_t)(n0 + row) * K + kt + col,
                  (char*)Wt + c * 4096 + wave * 1024);
    }
    asm volatile("s_waitcnt vmcnt(0)" ::: "memory");
    __syncthreads();

    const int wr = (wave >> 1) * 64, wc = (wave & 1) * 64;
#pragma unroll
    for (int kk = 0; kk < 2; ++kk) {
      short8 af[4], wf[4];
#pragma unroll
      for (int m = 0; m < 4; ++m) {
        const int row = wr + m * 16 + (lane & 15);
        const int colb = ((kk * 32 + (lane >> 4) * 8) * 2) ^ ((row & 7) << 4);
        af[m] = *(const short8*)((const char*)At + row * 128 + colb);
      }
#pragma unroll
      for (int n = 0; n < 4; ++n) {
        const int row = wc + n * 16 + (lane & 15);
        const int colb = ((kk * 32 + (lane >> 4) * 8) * 2) ^ ((row & 7) << 4);
        wf[n] = *(const short8*)((const char*)Wt + row * 128 + colb);
      }
#pragma unroll
      for (int m = 0; m < 4; ++m)
#pragma unroll
        for (int n = 0; n < 4; ++n)
          acc[m][n] = __builtin_amdgcn_mfma_f32_16x16x32_bf16(af[m], wf[n], acc[m][n], 0, 0, 0);
    }
    __syncthreads();
  }

  const int wr = (wave >> 1) * 64, wc = (wave & 1) * 64;
  const int g = lane >> 4, cl = lane & 15;
#pragma unroll
  for (int m = 0; m < 4; ++m) {
#pragma unroll
    for (int n = 0; n < 4; ++n) {
      const int ng = n0 + wc + n * 16 + cl;
      const float bv = bias[ng];
      if (TRANS_V) {
        const int mg = m0 + wr + m * 16 + g * 4;
        const int bb = mg >> 11;
        const int ss = mg & 2047;
        ushort4_t pk;
        pk.x = f2bf(acc[m][n][0] + bv);
        pk.y = f2bf(acc[m][n][1] + bv);
        pk.z = f2bf(acc[m][n][2] + bv);
        pk.w = f2bf(acc[m][n][3] + bv);
        *(ushort4_t*)((unsigned short*)Cout + ((size_t)bb * 1024 + ng) * 2048 + ss) = pk;
      } else {
#pragma unroll
        for (int r = 0; r < 4; ++r) {
          const int mg = m0 + wr + m * 16 + g * 4 + r;
          const float v = acc[m][n][r] + bv;
          if (OUT_F32)
            ((float*)Cout)[(size_t)mg * 1024 + ng] = v;
          else
            ((unsigned short*)Cout)[(size_t)mg * 1024 + ng] = f2bf(v);
        }
      }
    }
  }
}

// ---------------- flash attention (causal + padding mask) ----------------
// Causal-balanced: block processes q-tile pair {x, 15-x} -> uniform 34 kv-tiles.
__global__ __launch_bounds__(256) void attn_fwd(
    const unsigned short* __restrict__ Qp,   // [B*S][1024]
    const unsigned short* __restrict__ Kp,   // [B*S][1024]
    const unsigned short* __restrict__ Vt,   // [B][1024][2048] (transposed)
    const unsigned char* __restrict__ pmask, // [B][2048]
    unsigned short* __restrict__ Out) {      // [B*S][1024]
  __shared__ unsigned short Kt[64 * 64];
  __shared__ unsigned short Vl[64 * 64];
  __shared__ unsigned short Pl[4][32 * 72];
  __shared__ unsigned char msk[64];

  const int tid = threadIdx.x;
  const int wave = tid >> 6, lane = tid & 63;
  const int g = lane >> 4, cl = lane & 15;
  const int bh = blockIdx.y, b = bh >> 4, h = bh & 15;
  const int srow = tid >> 3, scol8 = tid & 7;
  // scale folded into exp2 domain: s*0.125 -> exp(x) == exp2(x*log2e)
  const float cs = 0.125f * 1.44269504088896f;

#pragma unroll 1
  for (int half = 0; half < 2; ++half) {
    const int qtile = half ? (15 - (int)blockIdx.x) : (int)blockIdx.x;
    const int q0 = qtile * 128;
    const int qw = q0 + wave * 32;

    short8 qf[2][2];
#pragma unroll
    for (int m = 0; m < 2; ++m)
#pragma unroll
      for (int kk = 0; kk < 2; ++kk)
        qf[m][kk] = *(const short8*)(Qp + (size_t)(b * S_ + qw + m * 16 + cl) * D_ +
                                     h * HD_ + kk * 32 + g * 8);

    float mrow[2][4], lrow[2][4];
    f32x4 oacc[2][4] = {};
#pragma unroll
    for (int m = 0; m < 2; ++m)
#pragma unroll
      for (int r = 0; r < 4; ++r) { mrow[m][r] = -INFINITY; lrow[m][r] = 0.f; }

    const int kvend = q0 + 128;
#pragma unroll 1
    for (int kv0 = 0; kv0 < kvend; kv0 += 64) {
#pragma unroll
      for (int c = 0; c < 2; ++c) {
        const int row = c * 32 + srow;
        const int col = (scol8 ^ (row & 7)) << 3;
        gload_lds16(Kp + (size_t)(b * S_ + kv0 + row) * D_ + h * HD_ + col,
                    (char*)Kt + c * 4096 + wave * 1024);
        gload_lds16(Vt + ((size_t)b * D_ + h * HD_ + row) * S_ + kv0 + col,
                    (char*)Vl + c * 4096 + wave * 1024);
      }
      if (tid < 64) msk[tid] = pmask[b * S_ + kv0 + tid];
      asm volatile("s_waitcnt vmcnt(0)" ::: "memory");
      __syncthreads();

      const bool active = (kv0 <= qw + 31);   // wave-uniform
      if (active) {
        // S = Q @ K^T
        f32x4 sc[2][4] = {};
#pragma unroll
        for (int kk = 0; kk < 2; ++kk) {
          short8 kf[4];
#pragma unroll
          for (int n = 0; n < 4; ++n) {
            const int row = n * 16 + cl;
            const int colb = ((kk * 32 + g * 8) * 2) ^ ((row & 7) << 4);
            kf[n] = *(const short8*)((const char*)Kt + row * 128 + colb);
          }
#pragma unroll
          for (int m = 0; m < 2; ++m)
#pragma unroll
            for (int n = 0; n < 4; ++n)
              sc[m][n] = __builtin_amdgcn_mfma_f32_16x16x32_bf16(qf[m][kk], kf[n], sc[m][n], 0, 0, 0);
        }

        // scale (exp2 domain) + causal + padding mask
        const bool anymask = (kv0 + 63 > qw);
        if (anymask) {
#pragma unroll
          for (int m = 0; m < 2; ++m)
#pragma unroll
            for (int n = 0; n < 4; ++n) {
              const int kv = kv0 + n * 16 + cl;
              const bool pmk = (msk[n * 16 + cl] != 0);
#pragma unroll
              for (int r = 0; r < 4; ++r) {
                const int qg = qw + m * 16 + g * 4 + r;
                const bool dead = (kv > qg) || pmk;
                sc[m][n][r] = dead ? -1e30f : sc[m][n][r] * cs;
              }
            }
        } else {
#pragma unroll
          for (int m = 0; m < 2; ++m)
#pragma unroll
            for (int n = 0; n < 4; ++n) {
              const bool pmk = (msk[n * 16 + cl] != 0);
#pragma unroll
              for (int r = 0; r < 4; ++r)
                sc[m][n][r] = pmk ? -1e30f : sc[m][n][r] * cs;
            }
        }

        // online softmax (exp2 domain), row state in 16-lane groups
#pragma unroll
        for (int m = 0; m < 2; ++m) {
#pragma unroll
          for (int r = 0; r < 4; ++r) {
            float mx = fmaxf(fmaxf(sc[m][0][r], sc[m][1][r]),
                             fmaxf(sc[m][2][r], sc[m][3][r]));
#pragma unroll
            for (int off = 1; off < 16; off <<= 1)
              mx = fmaxf(mx, __shfl_xor(mx, off, 64));
            const float mnew = fmaxf(mrow[m][r], mx);
            const float corr = exp2f(mrow[m][r] - mnew);
            mrow[m][r] = mnew;
            float rs = 0.f;
#pragma unroll
            for (int n = 0; n < 4; ++n) {
              const float p = exp2f(sc[m][n][r] - mnew);
              sc[m][n][r] = p;
              rs += p;
            }
#pragma unroll
            for (int off = 1; off < 16; off <<= 1)
              rs += __shfl_xor(rs, off, 64);
            lrow[m][r] = lrow[m][r] * corr + rs;
#pragma unroll
            for (int nd = 0; nd < 4; ++nd) oacc[m][nd][r] *= corr;
          }
        }

        // P -> LDS (bf16) to reach MFMA A-layout
        unsigned short* pw = &Pl[wave][0];
#pragma unroll
        for (int m = 0; m < 2; ++m)
#pragma unroll
          for (int n = 0; n < 4; ++n)
#pragma unroll
            for (int r = 0; r < 4; ++r)
              pw[(m * 16 + g * 4 + r) * 72 + n * 16 + cl] = f2bf(sc[m][n][r]);

        // O += P @ V
#pragma unroll
        for (int kk = 0; kk < 2; ++kk) {
          short8 pf[2], vf[4];
#pragma unroll
          for (int m = 0; m < 2; ++m)
            pf[m] = *(const short8*)(pw + (m * 16 + cl) * 72 + kk * 32 + g * 8);
#pragma unroll
          for (int nd = 0; nd < 4; ++nd) {
            const int row = nd * 16 + cl;
            const int colb = ((kk * 32 + g * 8) * 2) ^ ((row & 7) << 4);
            vf[nd] = *(const short8*)((const char*)Vl + row * 128 + colb);
          }
#pragma unroll
          for (int m = 0; m < 2; ++m)
#pragma unroll
            for (int nd = 0; nd < 4; ++nd)
              oacc[m][nd] = __builtin_amdgcn_mfma_f32_16x16x32_bf16(pf[m], vf[nd], oacc[m][nd], 0, 0, 0);
        }
      }
      __syncthreads();
    }

    // normalize + write
#pragma unroll
    for (int m = 0; m < 2; ++m) {
      float inv[4];
#pragma unroll
      for (int r = 0; r < 4; ++r) inv[r] = 1.f / lrow[m][r];
#pragma unroll
      for (int nd = 0; nd < 4; ++nd)
#pragma unroll
        for (int r = 0; r < 4; ++r) {
          const int qg = qw + m * 16 + g * 4 + r;
          Out[(size_t)(b * S_ + qg) * D_ + h * HD_ + nd * 16 + cl] =
              f2bf(oacc[m][nd][r] * inv[r]);
        }
    }
  }
}

// ---------------- launch ----------------
extern "C" void kernel_launch(void* const* d_in, const int* in_sizes, int n_in,
                              void* d_out, int out_size, void* d_ws, size_t ws_size,
                              hipStream_t stream) {
  (void)in_sizes; (void)n_in; (void)out_size; (void)ws_size;
  const float* q  = (const float*)d_in[0];
  const float* k  = (const float*)d_in[1];
  const float* v  = (const float*)d_in[2];
  const unsigned char* pm = (const unsigned char*)d_in[3];
  const float* Wq = (const float*)d_in[4];
  const float* bq = (const float*)d_in[5];
  const float* Wk = (const float*)d_in[6];
  const float* bk = (const float*)d_in[7];
  const float* Wv = (const float*)d_in[8];
  const float* bv = (const float*)d_in[9];
  const float* Wo = (const float*)d_in[10];
  const float* bo = (const float*)d_in[11];

  char* ws = (char*)d_ws;
  const size_t MB = 1024 * 1024;
  unsigned short* qb  = (unsigned short*)(ws + 0 * MB);
  unsigned short* kb  = (unsigned short*)(ws + 16 * MB);
  unsigned short* vb  = (unsigned short*)(ws + 32 * MB);
  unsigned short* Wqb = (unsigned short*)(ws + 48 * MB);
  unsigned short* Wkb = (unsigned short*)(ws + 50 * MB);
  unsigned short* Wvb = (unsigned short*)(ws + 52 * MB);
  unsigned short* Wob = (unsigned short*)(ws + 54 * MB);
  unsigned short* Qp  = (unsigned short*)(ws + 56 * MB);
  unsigned short* Kp  = (unsigned short*)(ws + 72 * MB);
  unsigned short* Vt  = (unsigned short*)(ws + 88 * MB);
  unsigned short* AO  = (unsigned short*)(ws + 104 * MB);

  const int n4_qkv = B_ * S_ * D_ / 4;  // 2,097,152
  const int n4_w   = 1024 * 1024 / 4;   // 262,144
  cvt3_f32_to_bf16<<<dim3(n4_qkv / 256, 3), dim3(256), 0, stream>>>(q, k, v, qb, kb, vb, n4_qkv);
  cvt4_f32_to_bf16<<<dim3(n4_w / 256, 4), dim3(256), 0, stream>>>(Wq, Wk, Wv, Wo, Wqb, Wkb, Wvb, Wob, n4_w);

  dim3 gg(8, 64), gb(256);
  gemm_bt<0, 0><<<gg, gb, 0, stream>>>(qb, Wqb, bq, Qp);
  gemm_bt<0, 0><<<gg, gb, 0, stream>>>(kb, Wkb, bk, Kp);
  gemm_bt<1, 0><<<gg, gb, 0, stream>>>(vb, Wvb, bv, Vt);

  attn_fwd<<<dim3(S_ / 256, B_ * NH_), dim3(256), 0, stream>>>(Qp, Kp, Vt, pm, AO);

  gemm_bt<0, 1><<<gg, gb, 0, stream>>>(AO, Wob, bo, (float*)d_out);
}